// Round 16
// baseline (1215.481 us; speedup 1.0000x reference)
//
#include <hip/hip_runtime.h>
#include <hip/hip_bf16.h>

#define B_ 4
#define C_ 80
#define T_ 800
#define R_ 3200   // B_*T_
#define DIN 160
#define NST 16
#define NCH 50    // time chunks (16 steps each)

typedef const float* fp;

__device__ __forceinline__ void g2l16(const float* g, float* l) {
  __builtin_amdgcn_global_load_lds(
      (const __attribute__((address_space(1))) void*)g,
      (__attribute__((address_space(3))) void*)l,
      16, 0, 0);
}
__device__ __forceinline__ void g2l4(const float* g, float* l) {
  __builtin_amdgcn_global_load_lds(
      (const __attribute__((address_space(1))) void*)g,
      (__attribute__((address_space(3))) void*)l,
      4, 0, 0);
}

// async linear stage of NF4 float4s into LDS (dest lane-linear per wave)
template<int NF4>
__device__ __forceinline__ void stageN(float* dst, const float* src, int tid) {
  int wv = tid >> 6, ln = tid & 63;
  constexpr int NP = (NF4 + 255) / 256;
  #pragma unroll
  for (int i = 0; i < NP; ++i) {
    int cbase = i * 256 + wv * 64;
    if (cbase + ln < NF4) {
      int lo = __builtin_amdgcn_readfirstlane(cbase * 4);
      g2l16(src + (cbase + ln) * 4, dst + lo);
    }
  }
}

__device__ __forceinline__ float blockSum(float v, float* sb) {
  for (int o = 32; o; o >>= 1) v += __shfl_xor(v, o);
  __syncthreads();
  if ((threadIdx.x & 63) == 0) sb[threadIdx.x >> 6] = v;
  __syncthreads();
  return sb[0] + sb[1] + sb[2] + sb[3];
}
__device__ __forceinline__ float blockMax(float v, float* sb) {
  for (int o = 32; o; o >>= 1) v = fmaxf(v, __shfl_xor(v, o));
  __syncthreads();
  if ((threadIdx.x & 63) == 0) sb[threadIdx.x >> 6] = v;
  __syncthreads();
  return fmaxf(fmaxf(sb[0], sb[1]), fmaxf(sb[2], sb[3]));
}

// ---- prep: W' = diag(g)W, u = colsum(W'), v = b@W (+bias), all 12 layers ----
__global__ __launch_bounds__(256) void prepw_k(fp in_proj, fp ff_w1,
    fp ln1_g, fp ln1_b, fp ln2_g, fp ln2_b, fp ff_b1,
    float* __restrict__ wp, float* __restrict__ uvb) {
  int idx = blockIdx.x * 256 + threadIdx.x;   // 0..7679
  int c = idx % 320, lm = idx / 320;
  int mat = lm & 1, l = lm >> 1;
  fp W = (mat ? ff_w1 : in_proj) + l * 25600;
  fp g = (mat ? ln2_g : ln1_g) + l * 80;
  fp b = (mat ? ln2_b : ln1_b) + l * 80;
  float* wpo = wp + lm * 25600;
  float u = 0.f, v = 0.f;
  for (int k = 0; k < 80; ++k) {
    float w = W[k * 320 + c];
    float gw = g[k] * w;
    wpo[k * 320 + c] = gw;
    u += gw;
    v += b[k] * w;
  }
  if (mat) v += ff_b1[l * 320 + c];
  uvb[lm * 640 + c] = u;
  uvb[lm * 640 + 320 + c] = v;
}

// ---- prep: padded-164 weight copies for gof/gfi -----------------------------
__global__ __launch_bounds__(256) void prepg_k(fp out_proj, fp ff_w2,
    const float* __restrict__ wp, float* __restrict__ wotp,
    float* __restrict__ w1pp, float* __restrict__ w2tp, float* __restrict__ wpnp) {
  int idx = blockIdx.x * 256 + threadIdx.x;
  if (idx >= 1102080) return;
  int l = idx / 91840, r = idx % 91840;
  if (r < 13120) {
    int c = r / 164, k = r % 164;
    wotp[l * 13120 + r] = (k < 160) ? out_proj[l * 12800 + k * 80 + c] : 0.f;
  } else if (r < 39360) {
    int r2 = r - 13120; int h = r2 / 13120, r3 = r2 % 13120;
    int kr = r3 / 164, cq = r3 % 164;
    w1pp[l * 26240 + r2] = (cq < 160) ? wp[(2 * l + 1) * 25600 + kr * 320 + h * 160 + cq] : 0.f;
  } else if (r < 65600) {
    int r2 = r - 39360; int h = r2 / 13120, r3 = r2 % 13120;
    int c = r3 / 164, k = r3 % 164;
    w2tp[l * 26240 + r2] = (k < 160) ? ff_w2[l * 25600 + (h * 160 + k) * 80 + c] : 0.f;
  } else {
    int r2 = r - 65600; int h = r2 / 13120, r3 = r2 % 13120;
    int kr = r3 / 164, cq = r3 % 164;
    float v = 0.f;
    if (l < 11 && cq < 160) v = wp[(2 * l + 2) * 25600 + kr * 320 + h * 160 + cq];
    wpnp[l * 26240 + r2] = v;
  }
}

// ---- prep: transpose+pad x_proj -> xptp[l][37][164] -------------------------
__global__ __launch_bounds__(256) void prepx_k(fp x_proj, float* __restrict__ xptp) {
  int idx = blockIdx.x * 256 + threadIdx.x;   // 12*6068 = 72816
  if (idx >= 72816) return;
  int l = idx / 6068, r = idx % 6068;
  int c = r / 164, k = r % 164;
  xptp[idx] = (k < 160) ? x_proj[l * 5920 + k * 37 + c] : 0.f;
}

// ---- CMN + transpose: feat [B,C,T] -> x [B*T, C] ----------------------------
__global__ __launch_bounds__(256) void cmn_k(fp feat, float* __restrict__ x) {
  int bc = blockIdx.x;
  int b = bc / C_, c = bc % C_;
  const float* f = feat + (b * C_ + c) * T_;
  __shared__ float sb[4];
  int tid = threadIdx.x;
  float v[4]; float s = 0.f;
  #pragma unroll
  for (int i = 0; i < 4; ++i) {
    int t = tid + i * 256;
    v[i] = (t < T_) ? f[t] : 0.f;
    s += v[i];
  }
  s = blockSum(s, sb);
  float mu = s * (1.f / T_);
  #pragma unroll
  for (int i = 0; i < 4; ++i) {
    int t = tid + i * 256;
    if (t < T_) x[(b * T_ + t) * C_ + c] = v[i] - mu;
  }
}

// ---- row stats (mu, rs) for LN fold (layer-0 entry only) --------------------
__global__ __launch_bounds__(256) void rstat_k(const float* __restrict__ in,
                                               float* __restrict__ must) {
  int row = blockIdx.x * 16 + (threadIdx.x >> 4);
  int c16 = threadIdx.x & 15;
  float s = 0.f, q = 0.f;
  #pragma unroll
  for (int m = 0; m < 5; ++m) {
    float v = in[row * 80 + c16 + 16 * m];
    s += v; q += v * v;
  }
  s += __shfl_xor(s, 1); s += __shfl_xor(s, 2);
  s += __shfl_xor(s, 4); s += __shfl_xor(s, 8);
  q += __shfl_xor(q, 1); q += __shfl_xor(q, 2);
  q += __shfl_xor(q, 4); q += __shfl_xor(q, 8);
  if (c16 == 0) {
    float mu = s * 0.0125f;
    float rs = rsqrtf(fmaxf(q * 0.0125f - mu * mu, 0.f) + 1e-5f);
    must[row * 2] = mu;
    must[row * 2 + 1] = rs;
  }
}

// ---- per-wave GEMM, K=80, TN=64; EPI 0: LN-fold (entry), 3: att1 ------------
template<int EPI>
__global__ __launch_bounds__(256, 4) void gw_k(const float* __restrict__ A,
    fp W, fp uv, const float* __restrict__ must, const float* __restrict__ extra,
    float* __restrict__ out, int N) {
  __shared__ float SL[5120 + 4 * 1280];
  int tid = threadIdx.x, wv = tid >> 6, ln = tid & 63;
  int bid = blockIdx.x;
  int c0 = (bid / 50) * 64;
  int row0 = ((bid % 50) * 4 + wv) * 16;
  for (int ch = wv; ch < 20; ch += 4) {
    int m = ch * 256 + ln * 4;
    int kr = m >> 6, cc = m & 63;
    int lo = __builtin_amdgcn_readfirstlane(ch * 256);
    g2l16(W + kr * N + c0 + cc, SL + lo);
  }
  int abase = __builtin_amdgcn_readfirstlane(5120 + wv * 1280);
  float* As = SL + 5120 + wv * 1280;
  #pragma unroll
  for (int i = 0; i < 5; ++i) {
    int m = i * 256 + ln * 4;
    int r = m / 80, kk = m - r * 80;
    g2l16(A + (row0 + r) * 80 + kk, SL + abase + i * 256);
  }
  __syncthreads();
  int rq = ln >> 4, c16 = ln & 15;
  float acc[4][4] = {};
  #pragma unroll 2
  for (int k4 = 0; k4 < 80; k4 += 4) {
    float4 a[4], w[4];
    #pragma unroll
    for (int i = 0; i < 4; ++i)
      a[i] = *(const float4*)&As[(rq * 4 + i) * 80 + k4];
    #pragma unroll
    for (int kk = 0; kk < 4; ++kk)
      w[kk] = *(const float4*)&SL[(k4 + kk) * 64 + c16 * 4];
    #pragma unroll
    for (int i = 0; i < 4; ++i) {
      acc[i][0] += a[i].x*w[0].x + a[i].y*w[1].x + a[i].z*w[2].x + a[i].w*w[3].x;
      acc[i][1] += a[i].x*w[0].y + a[i].y*w[1].y + a[i].z*w[2].y + a[i].w*w[3].y;
      acc[i][2] += a[i].x*w[0].z + a[i].y*w[1].z + a[i].z*w[2].z + a[i].w*w[3].z;
      acc[i][3] += a[i].x*w[0].w + a[i].y*w[1].w + a[i].z*w[2].w + a[i].w*w[3].w;
    }
  }
  float ua[4], va[4];
  if (EPI != 3) {
    *(float4*)ua = *(const float4*)&uv[c0 + c16 * 4];
    *(float4*)va = *(const float4*)&uv[N + c0 + c16 * 4];
  }
  #pragma unroll
  for (int i = 0; i < 4; ++i) {
    int row = row0 + rq * 4 + i;
    float mu = 0.f, rs = 1.f;
    if (EPI != 3) {
      float2 ms = *(const float2*)&must[row * 2];
      mu = ms.x; rs = ms.y;
    }
    float4 o;
    float* op = &o.x;
    #pragma unroll
    for (int j = 0; j < 4; ++j) {
      float v = acc[i][j];
      if (EPI == 3) {
        int c = c0 + c16 * 4 + j;
        v += extra[(row / T_) * 128 + c];
        v = fmaxf(v, 0.f);
        v = v * extra[512 + c] + extra[640 + c];
        v = tanhf(v);
      } else {
        v = rs * v - mu * rs * ua[j] + va[j];
      }
      op[j] = v;
    }
    *(float4*)&out[row * N + c0 + c16 * 4] = o;
  }
}

// ---- block-coop GEMM (pooling att2 only) ------------------------------------
template<int EPI, int KCH, int NKC>
__global__ __launch_bounds__(256, 4) void gc_k(const float* __restrict__ A,
    fp W, fp bias, float* __restrict__ out, int Astride) {
  constexpr int P = KCH + 4;
  __shared__ float As[16 * P];
  __shared__ float Wt[80 * P];
  int tid = threadIdx.x;
  int row0 = blockIdx.x * 16;
  int rr = tid >> 4, c16 = tid & 15;
  float acc[5] = {};
  for (int kc = 0; kc < NKC; ++kc) {
    if (kc) __syncthreads();
    #pragma unroll
    for (int i = 0; i < 16 * KCH / 256; ++i) {
      int e = tid + i * 256;
      int r = e / KCH, k = e - r * KCH;
      As[r * P + k] = A[(row0 + r) * Astride + kc * KCH + k];
    }
    #pragma unroll
    for (int i = 0; i < KCH * 80 / 256; ++i) {
      int e = tid + i * 256;
      int kr = e / 80, c = e - kr * 80;
      Wt[c * P + kr] = W[(kc * KCH + kr) * 80 + c];
    }
    __syncthreads();
    #pragma unroll 4
    for (int k4 = 0; k4 < KCH; k4 += 4) {
      float4 a = *(const float4*)&As[rr * P + k4];
      #pragma unroll
      for (int m = 0; m < 5; ++m) {
        float4 w = *(const float4*)&Wt[(c16 + 16 * m) * P + k4];
        acc[m] += a.x * w.x + a.y * w.y + a.z * w.z + a.w * w.w;
      }
    }
  }
  int row = row0 + rr;
  #pragma unroll
  for (int m = 0; m < 5; ++m) {
    int c = c16 + 16 * m;
    float v = acc[m];
    if (EPI == 4) v += bias[c];
    out[row * 80 + c] = v;
  }
}

// ---- cxfA: conv+SiLU + x_proj + dt+softplus + scan chunk summaries ----------
// grid 400 = (dir*4+b)*50 + tc ; summaries packed (prod, h_end) in hp
__global__ __launch_bounds__(256) void cxfA_k(const float* __restrict__ xz,
    fp cw, fp cb, fp xptl, fp dtw, fp dtb, fp A_log,
    float* __restrict__ xcf, float* __restrict__ xcbb,
    float* __restrict__ dbc2, float* __restrict__ dt2,
    float* __restrict__ hp) {
  __shared__ float As[16 * 164];
  __shared__ float xpT[37 * 164];
  __shared__ float dbcl[16 * 40];
  __shared__ float dtl[16 * 164];
  int bi = blockIdx.x;
  int tc = bi % 50; int rem = bi / 50;
  int b = rem & 3, dir = rem >> 2;
  int t0 = tc * 16;
  int tid = threadIdx.x;
  stageN<1517>(xpT, xptl, tid);   // async
  float* xco = dir ? xcbb : xcf;
  #pragma unroll
  for (int i = 0; i < 3; ++i) {
    int e = tid + i * 256;
    if (e < 640) {
      int ii = e / 40, d4 = (e - ii * 40) * 4;
      int t = t0 + ii;
      float4 acc = *(const float4*)&cb[d4];
      #pragma unroll
      for (int k = 0; k < 4; ++k) {
        int tt = t - 3 + k;
        if (tt >= 0) {
          int src = dir ? (T_ - 1 - tt) : tt;
          float4 xv = *(const float4*)&xz[(b * T_ + src) * 320 + d4];
          float4 wv = *(const float4*)&cw[k * DIN + d4];
          acc.x += wv.x * xv.x; acc.y += wv.y * xv.y;
          acc.z += wv.z * xv.z; acc.w += wv.w * xv.w;
        }
      }
      float4 o;
      o.x = acc.x / (1.f + __expf(-acc.x));
      o.y = acc.y / (1.f + __expf(-acc.y));
      o.z = acc.z / (1.f + __expf(-acc.z));
      o.w = acc.w / (1.f + __expf(-acc.w));
      *(float4*)&As[ii * 164 + d4] = o;
      *(float4*)&xco[(b * T_ + t) * DIN + d4] = o;
    }
  }
  __syncthreads();
  int rr = tid >> 4, c16 = tid & 15;
  int grow0 = dir * R_ + b * T_ + t0;
  {
    float a0 = 0.f, a1 = 0.f, a2 = 0.f;
    for (int k4 = 0; k4 < 160; k4 += 4) {
      float4 a = *(const float4*)&As[rr * 164 + k4];
      float4 w0 = *(const float4*)&xpT[c16 * 164 + k4];
      float4 w1 = *(const float4*)&xpT[(c16 + 16) * 164 + k4];
      a0 += a.x * w0.x + a.y * w0.y + a.z * w0.z + a.w * w0.w;
      a1 += a.x * w1.x + a.y * w1.y + a.z * w1.z + a.w * w1.w;
      if (c16 < 5) {
        float4 w2 = *(const float4*)&xpT[(c16 + 32) * 164 + k4];
        a2 += a.x * w2.x + a.y * w2.y + a.z * w2.z + a.w * w2.w;
      }
    }
    dbcl[rr * 40 + c16] = a0;
    dbcl[rr * 40 + c16 + 16] = a1;
    dbc2[(grow0 + rr) * 37 + c16] = a0;
    dbc2[(grow0 + rr) * 37 + c16 + 16] = a1;
    if (c16 < 5) {
      dbcl[rr * 40 + c16 + 32] = a2;
      dbc2[(grow0 + rr) * 37 + c16 + 32] = a2;
    }
  }
  __syncthreads();
  #pragma unroll
  for (int i = 0; i < 10; ++i) {
    int e = tid + i * 256;
    int ii = e / 160, d = e - ii * 160;
    float v = dtb[d];
    #pragma unroll
    for (int m = 0; m < 5; ++m) v += dbcl[ii * 40 + m] * dtw[m * DIN + d];
    v = fmaxf(v, 0.f) + __logf(1.f + __expf(-fabsf(v)));
    dtl[ii * 164 + d] = v;
    dt2[(grow0 + ii) * DIN + d] = v;
  }
  __syncthreads();
  // scan chunk summaries over the 16 local steps; k = dblk 0..9
  float h[10], dts[10], Ar[10];
  #pragma unroll
  for (int k = 0; k < 10; ++k) {
    Ar[k] = -__expf(A_log[k * 256 + tid]);
    h[k] = 0.f; dts[k] = 0.f;
  }
  for (int i = 0; i < 16; ++i) {
    float Bv = dbcl[i * 40 + 5 + (tid & 15)];
    #pragma unroll
    for (int k = 0; k < 10; ++k) {
      int d = k * 16 + (tid >> 4);
      float dtv = dtl[i * 164 + d];
      float a = __expf(dtv * Ar[k]);
      h[k] = a * h[k] + dtv * As[i * 164 + d] * Bv;
      dts[k] += dtv;
    }
  }
  int gb = (dir * 4 + b) * 10;
  #pragma unroll
  for (int k = 0; k < 10; ++k) {
    int idx = ((gb + k) * NCH + tc) * 256 + tid;
    hp[idx * 2] = __expf(dts[k] * Ar[k]);
    hp[idx * 2 + 1] = h[k];
  }
}

// ---- scanC16: in-block prefix (packed hp) + recompute 16-step chunk ---------
// grid 4000 = grp*50 + cc ; grp = (dir*4+b)*10 + dblk
__global__ __launch_bounds__(256) void scanC16_k(const float* __restrict__ dt2,
    const float* __restrict__ dbc2, const float* __restrict__ xcf,
    const float* __restrict__ xcbb, const float* __restrict__ xz,
    fp A_log, fp Dp, const float* __restrict__ hp, float* __restrict__ ygcat) {
  __shared__ float sdt[256], sX[256], sB[256], sC[256], sY[256];
  int bi = blockIdx.x;
  int cc = bi % NCH, grp = bi / NCH;
  int dblk = grp % 10; int rem = grp / 10;
  int b = rem & 3, dir = rem >> 2;
  int d0 = dblk * 16;
  int tid = threadIdx.x, i16 = tid >> 4, jj = tid & 15;
  const float* xc = dir ? xcbb : xcf;
  int t0 = cc * 16;
  {
    int wv = tid >> 6;
    int grow = dir * R_ + b * T_ + t0 + i16;
    int rloc = b * T_ + t0 + i16;
    int lo = __builtin_amdgcn_readfirstlane(wv * 64);
    g2l4(dt2 + grow * DIN + d0 + jj, sdt + lo);
    g2l4(xc + rloc * DIN + d0 + jj, sX + lo);
    g2l4(dbc2 + grow * 37 + 5 + jj, sB + lo);
    g2l4(dbc2 + grow * 37 + 21 + jj, sC + lo);
  }
  float Ar = -__expf(A_log[d0 * 16 + tid]);
  // prefix over earlier chunk summaries (cc is block-uniform)
  const float* hpb = hp + (long)(grp * NCH) * 512 + tid * 2;
  float h = 0.f;
  for (int c2 = 0; c2 < cc; ++c2) {
    float2 pe = *(const float2*)(hpb + c2 * 512);
    h = pe.x * h + pe.y;
  }
  __syncthreads();
  int dl = i16, n = jj;
  for (int i = 0; i < 16; ++i) {
    float dtv = sdt[i * 16 + dl];
    float a = __expf(dtv * Ar);
    h = a * h + dtv * sX[i * 16 + dl] * sB[i * 16 + n];
    float y = h * sC[i * 16 + n];
    y += __shfl_xor(y, 1);
    y += __shfl_xor(y, 2);
    y += __shfl_xor(y, 4);
    y += __shfl_xor(y, 8);
    if (n == 0) sY[i * 16 + dl] = y;
  }
  __syncthreads();
  {
    int t = t0 + i16;
    float xcv = sX[i16 * 16 + jj];
    int orow = dir ? (b * T_ + (T_ - 1 - t)) : (b * T_ + t);
    float z = xz[orow * 320 + 160 + d0 + jj];
    float sg = 1.f / (1.f + __expf(-z));
    ygcat[orow * 320 + dir * 160 + d0 + jj] = (sY[i16 * 16 + jj] + xcv * Dp[d0 + jj]) * (z * sg);
  }
}

// ---- gof: out_proj(sum fwd/bwd) + in-block LN2 + ff1-half + GELU ------------
__global__ __launch_bounds__(256, 2) void gof_k(const float* __restrict__ yg,
    fp wotp_l, fp w1pp_l, fp uv1, float* __restrict__ g1) {
  __shared__ float S[17120];
  float* Wt = S;             // [80][164]
  float* As = S + 13120;     // [16][164]
  float* sl = S + 15744;     // [16][84]
  float* ss = S + 17088;     // [32]
  int tid = threadIdx.x, row0 = blockIdx.x * 16, rr = tid >> 4, c16 = tid & 15;
  int h = blockIdx.y;
  stageN<3280>(Wt, wotp_l, tid);
  #pragma unroll
  for (int i = 0; i < 10; ++i) {
    int e = tid + i * 256; int r = e / 160, k = e - r * 160;
    As[r * 164 + k] = yg[(row0 + r) * 320 + k] + yg[(row0 + r) * 320 + 160 + k];
  }
  __syncthreads();
  {
    float acc[5] = {};
    #pragma unroll 4
    for (int k4 = 0; k4 < 160; k4 += 4) {
      float4 a = *(const float4*)&As[rr * 164 + k4];
      #pragma unroll
      for (int m = 0; m < 5; ++m) {
        float4 w = *(const float4*)&Wt[(c16 + 16 * m) * 164 + k4];
        acc[m] += a.x * w.x + a.y * w.y + a.z * w.z + a.w * w.w;
      }
    }
    float s = 0.f, q = 0.f;
    #pragma unroll
    for (int m = 0; m < 5; ++m) {
      float v = acc[m];
      sl[rr * 84 + c16 + 16 * m] = v;
      s += v; q += v * v;
    }
    s += __shfl_xor(s, 1); s += __shfl_xor(s, 2);
    s += __shfl_xor(s, 4); s += __shfl_xor(s, 8);
    q += __shfl_xor(q, 1); q += __shfl_xor(q, 2);
    q += __shfl_xor(q, 4); q += __shfl_xor(q, 8);
    if (c16 == 0) {
      float mu = s * 0.0125f;
      ss[rr * 2] = mu;
      ss[rr * 2 + 1] = rsqrtf(fmaxf(q * 0.0125f - mu * mu, 0.f) + 1e-5f);
    }
  }
  __syncthreads();
  stageN<3280>(Wt, w1pp_l + h * 13120, tid);
  __syncthreads();
  {
    float mu = ss[rr * 2], rs = ss[rr * 2 + 1];
    float a2[10] = {};
    for (int k = 0; k < 80; k += 4) {
      float4 av = *(const float4*)&sl[rr * 84 + k];
      #pragma unroll
      for (int m = 0; m < 10; ++m) {
        int c = c16 + 16 * m;
        a2[m] += av.x * Wt[k * 164 + c] + av.y * Wt[(k + 1) * 164 + c]
               + av.z * Wt[(k + 2) * 164 + c] + av.w * Wt[(k + 3) * 164 + c];
      }
    }
    #pragma unroll
    for (int m = 0; m < 10; ++m) {
      int c = h * 160 + c16 + 16 * m;
      float v = rs * a2[m] - mu * rs * uv1[c] + uv1[320 + c];
      v = 0.5f * v * (1.f + erff(v * 0.70710678118f));
      g1[(row0 + rr) * 320 + c] = v;
    }
  }
}

// ---- gfi: ff2 + bias + residual(xin->xout) + in-block LN1 + in_proj-half ----
template<int LAST>
__global__ __launch_bounds__(256, 2) void gfi_k(const float* __restrict__ g1,
    fp w2tp_l, fp fb2, const float* __restrict__ xin, float* __restrict__ xout,
    fp wpnp_l, fp uvn, float* __restrict__ xz) {
  __shared__ float S[17120];
  float* Wt = S;             // [80][164]
  float* As = S + 13120;     // [16][164]
  float* xn = S + 15744;     // [16][84]
  float* ss = S + 17088;     // [32]
  int tid = threadIdx.x, row0 = blockIdx.x * 16, rr = tid >> 4, c16 = tid & 15;
  int h = blockIdx.y;
  float acc2[5] = {};
  for (int kc = 0; kc < 2; ++kc) {
    if (kc) __syncthreads();
    stageN<3280>(Wt, w2tp_l + kc * 13120, tid);
    #pragma unroll
    for (int i = 0; i < 10; ++i) {
      int e = tid + i * 256; int r = e / 160, k = e - r * 160;
      As[r * 164 + k] = g1[(row0 + r) * 320 + kc * 160 + k];
    }
    __syncthreads();
    #pragma unroll 4
    for (int k4 = 0; k4 < 160; k4 += 4) {
      float4 a = *(const float4*)&As[rr * 164 + k4];
      #pragma unroll
      for (int m = 0; m < 5; ++m) {
        float4 w = *(const float4*)&Wt[(c16 + 16 * m) * 164 + k4];
        acc2[m] += a.x * w.x + a.y * w.y + a.z * w.z + a.w * w.w;
      }
    }
  }
  {
    float s = 0.f, q = 0.f;
    #pragma unroll
    for (int m = 0; m < 5; ++m) {
      int c = c16 + 16 * m;
      float v = acc2[m] + fb2[c] + xin[(row0 + rr) * 80 + c];
      xout[(row0 + rr) * 80 + c] = v;   // both y-blocks write identical values
      xn[rr * 84 + c] = v;
      s += v; q += v * v;
    }
    if (!LAST) {
      s += __shfl_xor(s, 1); s += __shfl_xor(s, 2);
      s += __shfl_xor(s, 4); s += __shfl_xor(s, 8);
      q += __shfl_xor(q, 1); q += __shfl_xor(q, 2);
      q += __shfl_xor(q, 4); q += __shfl_xor(q, 8);
      if (c16 == 0) {
        float mu = s * 0.0125f;
        ss[rr * 2] = mu;
        ss[rr * 2 + 1] = rsqrtf(fmaxf(q * 0.0125f - mu * mu, 0.f) + 1e-5f);
      }
    }
  }
  if (!LAST) {
    __syncthreads();
    stageN<3280>(Wt, wpnp_l + h * 13120, tid);
    __syncthreads();
    float mu = ss[rr * 2], rs = ss[rr * 2 + 1];
    float a3[10] = {};
    for (int k = 0; k < 80; k += 4) {
      float4 av = *(const float4*)&xn[rr * 84 + k];
      #pragma unroll
      for (int m = 0; m < 10; ++m) {
        int c = c16 + 16 * m;
        a3[m] += av.x * Wt[k * 164 + c] + av.y * Wt[(k + 1) * 164 + c]
               + av.z * Wt[(k + 2) * 164 + c] + av.w * Wt[(k + 3) * 164 + c];
      }
    }
    #pragma unroll
    for (int m = 0; m < 10; ++m) {
      int c = h * 160 + c16 + 16 * m;
      xz[(row0 + rr) * 320 + c] = rs * a3[m] - mu * rs * uvn[c] + uvn[320 + c];
    }
  }
}

// ---- pooling: per-(b,c) mean/std over T -------------------------------------
__global__ __launch_bounds__(256) void stats_k(const float* __restrict__ x,
                                               float* __restrict__ meanv, float* __restrict__ stdv) {
  int bc = blockIdx.x; int b = bc / C_, c = bc % C_;
  __shared__ float sb[4];
  int tid = threadIdx.x;
  float v[4]; float s = 0.f;
  #pragma unroll
  for (int i = 0; i < 4; ++i) {
    int t = tid + i * 256;
    v[i] = (t < T_) ? x[(b * T_ + t) * C_ + c] : 0.f;
    s += v[i];
  }
  s = blockSum(s, sb);
  float mu = s * (1.f / T_);
  float q = 0.f;
  #pragma unroll
  for (int i = 0; i < 4; ++i) {
    int t = tid + i * 256;
    if (t < T_) { float dd = v[i] - mu; q += dd * dd; }
  }
  q = blockSum(q, sb);
  if (tid == 0) { meanv[bc] = mu; stdv[bc] = sqrtf(fmaxf(q * (1.f / T_), 1e-12f)); }
}

// ---- att1 pack --------------------------------------------------------------
__global__ __launch_bounds__(256) void prep_k(const float* __restrict__ meanv,
    const float* __restrict__ stdv, fp w1, fp ab1, fp g1p, fp b1p, fp m1p, fp v1p,
    float* __restrict__ pack) {
  int idx = blockIdx.x * 256 + threadIdx.x;
  if (idx < 512) {
    int b = idx / 128, dcol = idx % 128;
    float acc = ab1[dcol];
    for (int c = 0; c < C_; ++c) {
      acc += meanv[b * C_ + c] * w1[(C_ + c) * 128 + dcol];
      acc += stdv[b * C_ + c] * w1[(2 * C_ + c) * 128 + dcol];
    }
    pack[idx] = acc;
  } else if (idx < 640) {
    int dcol = idx - 512;
    float kv = g1p[dcol] * rsqrtf(v1p[dcol] + 1e-5f);
    pack[512 + dcol] = kv;
    pack[640 + dcol] = b1p[dcol] - m1p[dcol] * kv;
  }
}

// ---- softmax over T + weighted stats + bn2 ----------------------------------
__global__ __launch_bounds__(256) void pool_k(const float* __restrict__ x,
    const float* __restrict__ scores, fp g2, fp b2, fp m2, fp v2,
    float* __restrict__ pooledn) {
  int bc = blockIdx.x; int b = bc / C_, c = bc % C_;
  __shared__ float sb[4];
  int tid = threadIdx.x;
  float sv[4], xv[4];
  float mx = -1e30f;
  #pragma unroll
  for (int i = 0; i < 4; ++i) {
    int t = tid + i * 256;
    if (t < T_) { sv[i] = scores[(b * T_ + t) * C_ + c]; xv[i] = x[(b * T_ + t) * C_ + c]; }
    else { sv[i] = -1e30f; xv[i] = 0.f; }
    mx = fmaxf(mx, sv[i]);
  }
  mx = blockMax(mx, sb);
  float se = 0.f, sx = 0.f, sxx = 0.f;
  #pragma unroll
  for (int i = 0; i < 4; ++i) {
    float e = expf(sv[i] - mx);
    se += e; sx += e * xv[i]; sxx += e * xv[i] * xv[i];
  }
  se = blockSum(se, sb);
  sx = blockSum(sx, sb);
  sxx = blockSum(sxx, sb);
  if (tid == 0) {
    float mu = sx / se;
    float sg = sqrtf(fmaxf(sxx / se - mu * mu, 1e-12f));
    int j0 = c, j1 = C_ + c;
    pooledn[b * 160 + j0] = (mu - m2[j0]) * rsqrtf(v2[j0] + 1e-5f) * g2[j0] + b2[j0];
    pooledn[b * 160 + j1] = (sg - m2[j1]) * rsqrtf(v2[j1] + 1e-5f) * g2[j1] + b2[j1];
  }
}

// ---- final fc ---------------------------------------------------------------
__global__ __launch_bounds__(256) void fc_k(const float* __restrict__ pooledn, fp fw, fp fb,
                                            float* __restrict__ out) {
  int idx = blockIdx.x * 256 + threadIdx.x;
  if (idx >= 4 * 192) return;
  int b = idx / 192, e = idx % 192;
  float acc = fb[e];
  for (int i = 0; i < 160; ++i) acc += pooledn[b * 160 + i] * fw[i * 192 + e];
  out[idx] = acc;
}

extern "C" void kernel_launch(void* const* d_in, const int* in_sizes, int n_in,
                              void* d_out, int out_size, void* d_ws, size_t ws_size,
                              hipStream_t stream) {
  fp feat   = (fp)d_in[0];
  fp ln1_g  = (fp)d_in[1];  fp ln1_b  = (fp)d_in[2];
  fp in_proj= (fp)d_in[3];
  fp conv_w = (fp)d_in[4];  fp conv_b = (fp)d_in[5];
  fp x_proj = (fp)d_in[6];
  fp dt_w   = (fp)d_in[7];  fp dt_b   = (fp)d_in[8];
  fp A_log  = (fp)d_in[9];  fp Dp     = (fp)d_in[10];
  fp out_proj=(fp)d_in[11];
  fp ln2_g  = (fp)d_in[12]; fp ln2_b  = (fp)d_in[13];
  fp ff_w1  = (fp)d_in[14]; fp ff_b1  = (fp)d_in[15];
  fp ff_w2  = (fp)d_in[16]; fp ff_b2  = (fp)d_in[17];
  fp att_w1 = (fp)d_in[18]; fp att_b1 = (fp)d_in[19];
  fp bn1_g  = (fp)d_in[20]; fp bn1_b  = (fp)d_in[21];
  fp bn1_m  = (fp)d_in[22]; fp bn1_v  = (fp)d_in[23];
  fp att_w2 = (fp)d_in[24]; fp att_b2 = (fp)d_in[25];
  fp bn2_g  = (fp)d_in[26]; fp bn2_b  = (fp)d_in[27];
  fp bn2_m  = (fp)d_in[28]; fp bn2_v  = (fp)d_in[29];
  fp fc_w   = (fp)d_in[30]; fp fc_b   = (fp)d_in[31];

  float* ws   = (float*)d_ws;
  float* x    = ws;               // 256000
  float* xz   = ws + 256000;      // 1024000
  float* xcf  = ws + 1280000;     // 512000
  float* xcb  = ws + 1792000;     // 512000
  float* dbc2 = ws + 2304000;     // 236800
  float* dt2  = ws + 2540800;     // 1024000
  float* hp   = ws + 3564800;     // 2048000 (80 grp x 50 x 256 x 2)
  float* ygcat= ws + 5612800;     // 1024000
  float* meanv= ws + 6636800;     // 320
  float* stdv = ws + 6637120;     // 320
  float* pack = ws + 6637440;     // 768
  float* pooledn = ws + 6638208;  // 640
  float* wp   = ws + 6638848;     // 614400
  float* uvb  = ws + 7253248;     // 15360
  float* mst_x= ws + 7268608;     // 6400
  float* xptp = ws + 7275008;     // 72816
  float* wotp = ws + 7347824;     // 157440
  float* w1pp = ws + 7505264;     // 314880
  float* w2tp = ws + 7820144;     // 314880
  float* wpnp = ws + 8135024;     // 314880
  float* x2   = ws + 8449904;     // 256000  (end 8705904 = 34.8 MiB)
  float* g1   = xz;               // alias: xz free after scanC
  float* a1b  = hp;               // alias: pooling only
  float* sc   = dt2;              // alias: pooling only
  float* xb[2] = { x, x2 };

  prepw_k<<<30, 256, 0, stream>>>(in_proj, ff_w1, ln1_g, ln1_b, ln2_g, ln2_b,
                                  ff_b1, wp, uvb);
  prepg_k<<<4305, 256, 0, stream>>>(out_proj, ff_w2, wp, wotp, w1pp, w2tp, wpnp);
  prepx_k<<<285, 256, 0, stream>>>(x_proj, xptp);
  cmn_k<<<320, 256, 0, stream>>>(feat, x);
  rstat_k<<<200, 256, 0, stream>>>(x, mst_x);
  gw_k<0><<<250, 256, 0, stream>>>(x, wp, uvb, mst_x, nullptr, xz, 320);

  for (int l = 0; l < 12; ++l) {
    cxfA_k<<<400, 256, 0, stream>>>(xz, conv_w + l * 640, conv_b + l * 160,
                                    xptp + l * 6068, dt_w + l * 800, dt_b + l * 160,
                                    A_log + l * 2560, xcf, xcb, dbc2, dt2, hp);
    scanC16_k<<<4000, 256, 0, stream>>>(dt2, dbc2, xcf, xcb, xz,
                                        A_log + l * 2560, Dp + l * 160, hp, ygcat);
    gof_k<<<dim3(200, 2), 256, 0, stream>>>(ygcat, wotp + l * 13120,
                                            w1pp + l * 26240,
                                            uvb + (2 * l + 1) * 640, g1);
    if (l < 11)
      gfi_k<0><<<dim3(200, 2), 256, 0, stream>>>(g1, w2tp + l * 26240,
                                                 ff_b2 + l * 80, xb[l & 1],
                                                 xb[(l + 1) & 1],
                                                 wpnp + l * 26240,
                                                 uvb + (2 * l + 2) * 640, xz);
    else
      gfi_k<1><<<dim3(200, 2), 256, 0, stream>>>(g1, w2tp + l * 26240,
                                                 ff_b2 + l * 80, xb[l & 1],
                                                 xb[(l + 1) & 1],
                                                 wpnp + l * 26240, uvb, xz);
  }

  stats_k<<<320, 256, 0, stream>>>(x, meanv, stdv);
  prep_k<<<3, 256, 0, stream>>>(meanv, stdv, att_w1, att_b1, bn1_g, bn1_b, bn1_m, bn1_v, pack);
  gw_k<3><<<100, 256, 0, stream>>>(x, att_w1, nullptr, nullptr, pack, a1b, 128);
  gc_k<4, 128, 1><<<200, 256, 0, stream>>>(a1b, att_w2, att_b2, sc, 128);
  pool_k<<<320, 256, 0, stream>>>(x, sc, bn2_g, bn2_b, bn2_m, bn2_v, pooledn);
  fc_k<<<3, 256, 0, stream>>>(pooledn, fc_w, fc_b, (float*)d_out);
}

// Round 17
// 1141.873 us; speedup vs baseline: 1.0645x; 1.0645x over previous
//
#include <hip/hip_runtime.h>
#include <hip/hip_bf16.h>

#define B_ 4
#define C_ 80
#define T_ 800
#define R_ 3200   // B_*T_
#define DIN 160
#define NST 16
#define NC 16     // time chunks for parallel scan
#define LCH 50    // T_/NC

typedef const float* fp;

__device__ __forceinline__ void g2l16(const float* g, float* l) {
  __builtin_amdgcn_global_load_lds(
      (const __attribute__((address_space(1))) void*)g,
      (__attribute__((address_space(3))) void*)l,
      16, 0, 0);
}

// async linear stage of NF4 float4s into LDS (dest lane-linear per wave)
template<int NF4>
__device__ __forceinline__ void stageN(float* dst, const float* src, int tid) {
  int wv = tid >> 6, ln = tid & 63;
  constexpr int NP = (NF4 + 255) / 256;
  #pragma unroll
  for (int i = 0; i < NP; ++i) {
    int cbase = i * 256 + wv * 64;
    if (cbase + ln < NF4) {
      int lo = __builtin_amdgcn_readfirstlane(cbase * 4);
      g2l16(src + (cbase + ln) * 4, dst + lo);
    }
  }
}

__device__ __forceinline__ float blockSum(float v, float* sb) {
  for (int o = 32; o; o >>= 1) v += __shfl_xor(v, o);
  __syncthreads();
  if ((threadIdx.x & 63) == 0) sb[threadIdx.x >> 6] = v;
  __syncthreads();
  return sb[0] + sb[1] + sb[2] + sb[3];
}
__device__ __forceinline__ float blockMax(float v, float* sb) {
  for (int o = 32; o; o >>= 1) v = fmaxf(v, __shfl_xor(v, o));
  __syncthreads();
  if ((threadIdx.x & 63) == 0) sb[threadIdx.x >> 6] = v;
  __syncthreads();
  return fmaxf(fmaxf(sb[0], sb[1]), fmaxf(sb[2], sb[3]));
}

// ---- prep: W' = diag(g)W, u = colsum(W'), v = b@W (+bias), all 12 layers ----
__global__ __launch_bounds__(256) void prepw_k(fp in_proj, fp ff_w1,
    fp ln1_g, fp ln1_b, fp ln2_g, fp ln2_b, fp ff_b1,
    float* __restrict__ wp, float* __restrict__ uvb) {
  int idx = blockIdx.x * 256 + threadIdx.x;   // 0..7679
  int c = idx % 320, lm = idx / 320;
  int mat = lm & 1, l = lm >> 1;
  fp W = (mat ? ff_w1 : in_proj) + l * 25600;
  fp g = (mat ? ln2_g : ln1_g) + l * 80;
  fp b = (mat ? ln2_b : ln1_b) + l * 80;
  float* wpo = wp + lm * 25600;
  float u = 0.f, v = 0.f;
  for (int k = 0; k < 80; ++k) {
    float w = W[k * 320 + c];
    float gw = g[k] * w;
    wpo[k * 320 + c] = gw;
    u += gw;
    v += b[k] * w;
  }
  if (mat) v += ff_b1[l * 320 + c];
  uvb[lm * 640 + c] = u;
  uvb[lm * 640 + 320 + c] = v;
}

// ---- prep: padded-164 weight copies for gof/gfi -----------------------------
__global__ __launch_bounds__(256) void prepg_k(fp out_proj, fp ff_w2,
    const float* __restrict__ wp, float* __restrict__ wotp,
    float* __restrict__ w1pp, float* __restrict__ w2tp, float* __restrict__ wpnp) {
  int idx = blockIdx.x * 256 + threadIdx.x;
  if (idx >= 1102080) return;
  int l = idx / 91840, r = idx % 91840;
  if (r < 13120) {
    int c = r / 164, k = r % 164;
    wotp[l * 13120 + r] = (k < 160) ? out_proj[l * 12800 + k * 80 + c] : 0.f;
  } else if (r < 39360) {
    int r2 = r - 13120; int h = r2 / 13120, r3 = r2 % 13120;
    int kr = r3 / 164, cq = r3 % 164;
    w1pp[l * 26240 + r2] = (cq < 160) ? wp[(2 * l + 1) * 25600 + kr * 320 + h * 160 + cq] : 0.f;
  } else if (r < 65600) {
    int r2 = r - 39360; int h = r2 / 13120, r3 = r2 % 13120;
    int c = r3 / 164, k = r3 % 164;
    w2tp[l * 26240 + r2] = (k < 160) ? ff_w2[l * 25600 + (h * 160 + k) * 80 + c] : 0.f;
  } else {
    int r2 = r - 65600; int h = r2 / 13120, r3 = r2 % 13120;
    int kr = r3 / 164, cq = r3 % 164;
    float v = 0.f;
    if (l < 11 && cq < 160) v = wp[(2 * l + 2) * 25600 + kr * 320 + h * 160 + cq];
    wpnp[l * 26240 + r2] = v;
  }
}

// ---- prep: transpose+pad x_proj -> xptp[l][37][164] -------------------------
__global__ __launch_bounds__(256) void prepx_k(fp x_proj, float* __restrict__ xptp) {
  int idx = blockIdx.x * 256 + threadIdx.x;   // 12*6068 = 72816
  if (idx >= 72816) return;
  int l = idx / 6068, r = idx % 6068;
  int c = r / 164, k = r % 164;
  xptp[idx] = (k < 160) ? x_proj[l * 5920 + k * 37 + c] : 0.f;
}

// ---- CMN + transpose: feat [B,C,T] -> x [B*T, C] ----------------------------
__global__ __launch_bounds__(256) void cmn_k(fp feat, float* __restrict__ x) {
  int bc = blockIdx.x;
  int b = bc / C_, c = bc % C_;
  const float* f = feat + (b * C_ + c) * T_;
  __shared__ float sb[4];
  int tid = threadIdx.x;
  float v[4]; float s = 0.f;
  #pragma unroll
  for (int i = 0; i < 4; ++i) {
    int t = tid + i * 256;
    v[i] = (t < T_) ? f[t] : 0.f;
    s += v[i];
  }
  s = blockSum(s, sb);
  float mu = s * (1.f / T_);
  #pragma unroll
  for (int i = 0; i < 4; ++i) {
    int t = tid + i * 256;
    if (t < T_) x[(b * T_ + t) * C_ + c] = v[i] - mu;
  }
}

// ---- row stats (mu, rs) for LN fold (layer-0 entry only) --------------------
__global__ __launch_bounds__(256) void rstat_k(const float* __restrict__ in,
                                               float* __restrict__ must) {
  int row = blockIdx.x * 16 + (threadIdx.x >> 4);
  int c16 = threadIdx.x & 15;
  float s = 0.f, q = 0.f;
  #pragma unroll
  for (int m = 0; m < 5; ++m) {
    float v = in[row * 80 + c16 + 16 * m];
    s += v; q += v * v;
  }
  s += __shfl_xor(s, 1); s += __shfl_xor(s, 2);
  s += __shfl_xor(s, 4); s += __shfl_xor(s, 8);
  q += __shfl_xor(q, 1); q += __shfl_xor(q, 2);
  q += __shfl_xor(q, 4); q += __shfl_xor(q, 8);
  if (c16 == 0) {
    float mu = s * 0.0125f;
    float rs = rsqrtf(fmaxf(q * 0.0125f - mu * mu, 0.f) + 1e-5f);
    must[row * 2] = mu;
    must[row * 2 + 1] = rs;
  }
}

// ---- per-wave GEMM, K=80, TN=64; EPI 0: LN-fold (entry), 3: att1 ------------
template<int EPI>
__global__ __launch_bounds__(256, 4) void gw_k(const float* __restrict__ A,
    fp W, fp uv, const float* __restrict__ must, const float* __restrict__ extra,
    float* __restrict__ out, int N) {
  __shared__ float SL[5120 + 4 * 1280];
  int tid = threadIdx.x, wv = tid >> 6, ln = tid & 63;
  int bid = blockIdx.x;
  int c0 = (bid / 50) * 64;
  int row0 = ((bid % 50) * 4 + wv) * 16;
  for (int ch = wv; ch < 20; ch += 4) {
    int m = ch * 256 + ln * 4;
    int kr = m >> 6, cc = m & 63;
    int lo = __builtin_amdgcn_readfirstlane(ch * 256);
    g2l16(W + kr * N + c0 + cc, SL + lo);
  }
  int abase = __builtin_amdgcn_readfirstlane(5120 + wv * 1280);
  float* As = SL + 5120 + wv * 1280;
  #pragma unroll
  for (int i = 0; i < 5; ++i) {
    int m = i * 256 + ln * 4;
    int r = m / 80, kk = m - r * 80;
    g2l16(A + (row0 + r) * 80 + kk, SL + abase + i * 256);
  }
  __syncthreads();
  int rq = ln >> 4, c16 = ln & 15;
  float acc[4][4] = {};
  #pragma unroll 2
  for (int k4 = 0; k4 < 80; k4 += 4) {
    float4 a[4], w[4];
    #pragma unroll
    for (int i = 0; i < 4; ++i)
      a[i] = *(const float4*)&As[(rq * 4 + i) * 80 + k4];
    #pragma unroll
    for (int kk = 0; kk < 4; ++kk)
      w[kk] = *(const float4*)&SL[(k4 + kk) * 64 + c16 * 4];
    #pragma unroll
    for (int i = 0; i < 4; ++i) {
      acc[i][0] += a[i].x*w[0].x + a[i].y*w[1].x + a[i].z*w[2].x + a[i].w*w[3].x;
      acc[i][1] += a[i].x*w[0].y + a[i].y*w[1].y + a[i].z*w[2].y + a[i].w*w[3].y;
      acc[i][2] += a[i].x*w[0].z + a[i].y*w[1].z + a[i].z*w[2].z + a[i].w*w[3].z;
      acc[i][3] += a[i].x*w[0].w + a[i].y*w[1].w + a[i].z*w[2].w + a[i].w*w[3].w;
    }
  }
  float ua[4], va[4];
  if (EPI != 3) {
    *(float4*)ua = *(const float4*)&uv[c0 + c16 * 4];
    *(float4*)va = *(const float4*)&uv[N + c0 + c16 * 4];
  }
  #pragma unroll
  for (int i = 0; i < 4; ++i) {
    int row = row0 + rq * 4 + i;
    float mu = 0.f, rs = 1.f;
    if (EPI != 3) {
      float2 ms = *(const float2*)&must[row * 2];
      mu = ms.x; rs = ms.y;
    }
    float4 o;
    float* op = &o.x;
    #pragma unroll
    for (int j = 0; j < 4; ++j) {
      float v = acc[i][j];
      if (EPI == 3) {
        int c = c0 + c16 * 4 + j;
        v += extra[(row / T_) * 128 + c];
        v = fmaxf(v, 0.f);
        v = v * extra[512 + c] + extra[640 + c];
        v = tanhf(v);
      } else {
        v = rs * v - mu * rs * ua[j] + va[j];
      }
      op[j] = v;
    }
    *(float4*)&out[row * N + c0 + c16 * 4] = o;
  }
}

// ---- block-coop GEMM (pooling att2 only) ------------------------------------
template<int EPI, int KCH, int NKC>
__global__ __launch_bounds__(256, 4) void gc_k(const float* __restrict__ A,
    fp W, fp bias, float* __restrict__ out, int Astride) {
  constexpr int P = KCH + 4;
  __shared__ float As[16 * P];
  __shared__ float Wt[80 * P];
  int tid = threadIdx.x;
  int row0 = blockIdx.x * 16;
  int rr = tid >> 4, c16 = tid & 15;
  float acc[5] = {};
  for (int kc = 0; kc < NKC; ++kc) {
    if (kc) __syncthreads();
    #pragma unroll
    for (int i = 0; i < 16 * KCH / 256; ++i) {
      int e = tid + i * 256;
      int r = e / KCH, k = e - r * KCH;
      As[r * P + k] = A[(row0 + r) * Astride + kc * KCH + k];
    }
    #pragma unroll
    for (int i = 0; i < KCH * 80 / 256; ++i) {
      int e = tid + i * 256;
      int kr = e / 80, c = e - kr * 80;
      Wt[c * P + kr] = W[(kc * KCH + kr) * 80 + c];
    }
    __syncthreads();
    #pragma unroll 4
    for (int k4 = 0; k4 < KCH; k4 += 4) {
      float4 a = *(const float4*)&As[rr * P + k4];
      #pragma unroll
      for (int m = 0; m < 5; ++m) {
        float4 w = *(const float4*)&Wt[(c16 + 16 * m) * P + k4];
        acc[m] += a.x * w.x + a.y * w.y + a.z * w.z + a.w * w.w;
      }
    }
  }
  int row = row0 + rr;
  #pragma unroll
  for (int m = 0; m < 5; ++m) {
    int c = c16 + 16 * m;
    float v = acc[m];
    if (EPI == 4) v += bias[c];
    out[row * 80 + c] = v;
  }
}

// ---- cxf: conv+SiLU + x_proj + dt+softplus; dbc2 padded to stride 40 --------
// dbc2 layout: dt at 0..4, B at 8..23, C at 24..39 (16B-aligned fields)
__global__ __launch_bounds__(256) void cxf_k(const float* __restrict__ xz,
    fp cw, fp cb, fp xptl, fp dtw, fp dtb,
    float* __restrict__ xcf, float* __restrict__ xcbb,
    float* __restrict__ dbc2, float* __restrict__ dt2) {
  __shared__ float As[16 * 164];
  __shared__ float xpT[37 * 164];
  __shared__ float dbcl[16 * 40];
  int bi = blockIdx.x;
  int tc = bi % 50; int rem = bi / 50;
  int b = rem & 3, dir = rem >> 2;
  int t0 = tc * 16;
  int tid = threadIdx.x;
  stageN<1517>(xpT, xptl, tid);   // async
  float* xco = dir ? xcbb : xcf;
  #pragma unroll
  for (int i = 0; i < 3; ++i) {
    int e = tid + i * 256;
    if (e < 640) {
      int ii = e / 40, d4 = (e - ii * 40) * 4;
      int t = t0 + ii;
      float4 acc = *(const float4*)&cb[d4];
      #pragma unroll
      for (int k = 0; k < 4; ++k) {
        int tt = t - 3 + k;
        if (tt >= 0) {
          int src = dir ? (T_ - 1 - tt) : tt;
          float4 xv = *(const float4*)&xz[(b * T_ + src) * 320 + d4];
          float4 wv = *(const float4*)&cw[k * DIN + d4];
          acc.x += wv.x * xv.x; acc.y += wv.y * xv.y;
          acc.z += wv.z * xv.z; acc.w += wv.w * xv.w;
        }
      }
      float4 o;
      o.x = acc.x / (1.f + __expf(-acc.x));
      o.y = acc.y / (1.f + __expf(-acc.y));
      o.z = acc.z / (1.f + __expf(-acc.z));
      o.w = acc.w / (1.f + __expf(-acc.w));
      *(float4*)&As[ii * 164 + d4] = o;
      *(float4*)&xco[(b * T_ + t) * DIN + d4] = o;
    }
  }
  __syncthreads();
  int rr = tid >> 4, c16 = tid & 15;
  int grow0 = dir * R_ + b * T_ + t0;
  {
    float a0 = 0.f, a1 = 0.f, a2 = 0.f;
    for (int k4 = 0; k4 < 160; k4 += 4) {
      float4 a = *(const float4*)&As[rr * 164 + k4];
      float4 w0 = *(const float4*)&xpT[c16 * 164 + k4];
      float4 w1 = *(const float4*)&xpT[(c16 + 16) * 164 + k4];
      a0 += a.x * w0.x + a.y * w0.y + a.z * w0.z + a.w * w0.w;
      a1 += a.x * w1.x + a.y * w1.y + a.z * w1.z + a.w * w1.w;
      if (c16 < 5) {
        float4 w2 = *(const float4*)&xpT[(c16 + 32) * 164 + k4];
        a2 += a.x * w2.x + a.y * w2.y + a.z * w2.z + a.w * w2.w;
      }
    }
    // local dbcl keeps original col mapping (0..36)
    dbcl[rr * 40 + c16] = a0;
    dbcl[rr * 40 + c16 + 16] = a1;
    // global dbc2 padded: col c -> c<5 ? c : (c<21 ? c+3 : c+6)
    int c0n = (c16 < 5) ? c16 : c16 + 3;
    int c1n = (c16 < 5) ? (c16 + 19) : (c16 + 22);
    dbc2[(grow0 + rr) * 40 + c0n] = a0;
    dbc2[(grow0 + rr) * 40 + c1n] = a1;
    if (c16 < 5) {
      dbcl[rr * 40 + c16 + 32] = a2;
      dbc2[(grow0 + rr) * 40 + c16 + 38] = a2;
    }
  }
  __syncthreads();
  #pragma unroll
  for (int i = 0; i < 10; ++i) {
    int e = tid + i * 256;
    int ii = e / 160, d = e - ii * 160;
    float v = dtb[d];
    #pragma unroll
    for (int m = 0; m < 5; ++m) v += dbcl[ii * 40 + m] * dtw[m * DIN + d];
    v = fmaxf(v, 0.f) + __logf(1.f + __expf(-fabsf(v)));
    dt2[(grow0 + ii) * DIN + d] = v;
  }
}

// ---- scanA: per-chunk (prod, h_end); 16B async staging; packed hp -----------
__global__ __launch_bounds__(256) void scanA_k(const float* __restrict__ dt2,
    const float* __restrict__ xcf, const float* __restrict__ xcbb,
    const float* __restrict__ dbc2, fp A_log, float* __restrict__ hp) {
  __shared__ float sdt[800], sX[800], sB[800];
  int bi = blockIdx.x;
  int cch = bi % NC; int rem = bi / NC;
  int dblk = rem % 10; rem /= 10;
  int b = rem % 4; int dir = rem / 4;
  int d0 = dblk * 16;
  int tid = threadIdx.x, dl = tid >> 4, n = tid & 15;
  int d = d0 + dl;
  const float* xc = dir ? xcbb : xcf;
  int rbase = dir * R_ + b * T_ + cch * LCH;
  int rloc0 = b * T_ + cch * LCH;
  {
    int q = tid;
    if (q < 200) {
      int ii = q >> 2, jm = (q & 3) * 4;
      int lo = __builtin_amdgcn_readfirstlane((q & ~63) * 4);
      g2l16(dt2 + (rbase + ii) * DIN + d0 + jm, sdt + lo);
      g2l16(xc + (rloc0 + ii) * DIN + d0 + jm, sX + lo);
      g2l16(dbc2 + (rbase + ii) * 40 + 8 + jm, sB + lo);
    }
  }
  float Areg = -__expf(A_log[d * NST + n]);
  __syncthreads();
  float h = 0.f, dts = 0.f;
  #pragma unroll 2
  for (int i = 0; i < LCH; ++i) {
    float dtv = sdt[i * 16 + dl];
    float aa = __expf(dtv * Areg);
    h = aa * h + dtv * sX[i * 16 + dl] * sB[i * 16 + n];
    dts += dtv;
  }
  int idx = bi * 256 + tid;
  hp[idx * 2] = __expf(dts * Areg);
  hp[idx * 2 + 1] = h;
}

// ---- scanC: fused prefix (packed hp) + recompute + gated write; 16B staging -
__global__ __launch_bounds__(256) void scanC_k(const float* __restrict__ dt2,
    const float* __restrict__ dbc2, const float* __restrict__ xcf,
    const float* __restrict__ xcbb, const float* __restrict__ xz,
    fp A_log, fp Dp, const float* __restrict__ hp, float* __restrict__ ygcat) {
  __shared__ float sdt[800], sX[800], sB[800], sC[800], sY[800];
  int bi = blockIdx.x;
  int cch = bi % NC; int rem = bi / NC;
  int dblk = rem % 10; rem /= 10;
  int b = rem % 4; int dir = rem / 4;
  int d0 = dblk * 16;
  int tid = threadIdx.x, dl = tid >> 4, n = tid & 15;
  int d = d0 + dl;
  const float* xc = dir ? xcbb : xcf;
  int rbase = dir * R_ + b * T_ + cch * LCH;
  int rloc0 = b * T_ + cch * LCH;
  {
    int q = tid;
    if (q < 200) {
      int ii = q >> 2, jm = (q & 3) * 4;
      int lo = __builtin_amdgcn_readfirstlane((q & ~63) * 4);
      g2l16(dt2 + (rbase + ii) * DIN + d0 + jm, sdt + lo);
      g2l16(xc + (rloc0 + ii) * DIN + d0 + jm, sX + lo);
      g2l16(dbc2 + (rbase + ii) * 40 + 8 + jm, sB + lo);
      g2l16(dbc2 + (rbase + ii) * 40 + 24 + jm, sC + lo);
    }
  }
  float Areg = -__expf(A_log[d * NST + n]);
  // fused prefix over earlier chunk summaries (packed float2)
  const float* hpb = hp + (long)((bi / NC) * (NC * 256) + tid) * 2;
  float h = 0.f;
  #pragma unroll
  for (int cc = 0; cc < NC; ++cc) {
    float2 pe = *(const float2*)(hpb + cc * 512);
    if (cc < cch) h = pe.x * h + pe.y;
  }
  __syncthreads();
  for (int i = 0; i < LCH; ++i) {
    float dtv = sdt[i * 16 + dl];
    float a = __expf(dtv * Areg);
    h = a * h + dtv * sX[i * 16 + dl] * sB[i * 16 + n];
    float y = h * sC[i * 16 + n];
    y += __shfl_xor(y, 1);
    y += __shfl_xor(y, 2);
    y += __shfl_xor(y, 4);
    y += __shfl_xor(y, 8);
    if (n == 0) sY[i * 16 + dl] = y;
  }
  __syncthreads();
  for (int e = tid; e < LCH * 16; e += 256) {
    int i = e >> 4, jj = e & 15;
    int t = cch * LCH + i;
    float xcv = sX[i * 16 + jj];
    int orow = dir ? (b * T_ + (T_ - 1 - t)) : (b * T_ + t);
    float z = xz[orow * 320 + 160 + d0 + jj];
    float sg = 1.f / (1.f + __expf(-z));
    ygcat[orow * 320 + dir * 160 + d0 + jj] = (sY[i * 16 + jj] + xcv * Dp[d0 + jj]) * (z * sg);
  }
}

// ---- gof: out_proj(sum fwd/bwd) + in-block LN2 + ff1-half + GELU ------------
__global__ __launch_bounds__(256, 2) void gof_k(const float* __restrict__ yg,
    fp wotp_l, fp w1pp_l, fp uv1, float* __restrict__ g1) {
  __shared__ float S[17120];
  float* Wt = S;             // [80][164]
  float* As = S + 13120;     // [16][164]
  float* sl = S + 15744;     // [16][84]
  float* ss = S + 17088;     // [32]
  int tid = threadIdx.x, row0 = blockIdx.x * 16, rr = tid >> 4, c16 = tid & 15;
  int h = blockIdx.y;
  stageN<3280>(Wt, wotp_l, tid);
  #pragma unroll
  for (int i = 0; i < 10; ++i) {
    int e = tid + i * 256; int r = e / 160, k = e - r * 160;
    As[r * 164 + k] = yg[(row0 + r) * 320 + k] + yg[(row0 + r) * 320 + 160 + k];
  }
  __syncthreads();
  {
    float acc[5] = {};
    #pragma unroll 4
    for (int k4 = 0; k4 < 160; k4 += 4) {
      float4 a = *(const float4*)&As[rr * 164 + k4];
      #pragma unroll
      for (int m = 0; m < 5; ++m) {
        float4 w = *(const float4*)&Wt[(c16 + 16 * m) * 164 + k4];
        acc[m] += a.x * w.x + a.y * w.y + a.z * w.z + a.w * w.w;
      }
    }
    float s = 0.f, q = 0.f;
    #pragma unroll
    for (int m = 0; m < 5; ++m) {
      float v = acc[m];
      sl[rr * 84 + c16 + 16 * m] = v;
      s += v; q += v * v;
    }
    s += __shfl_xor(s, 1); s += __shfl_xor(s, 2);
    s += __shfl_xor(s, 4); s += __shfl_xor(s, 8);
    q += __shfl_xor(q, 1); q += __shfl_xor(q, 2);
    q += __shfl_xor(q, 4); q += __shfl_xor(q, 8);
    if (c16 == 0) {
      float mu = s * 0.0125f;
      ss[rr * 2] = mu;
      ss[rr * 2 + 1] = rsqrtf(fmaxf(q * 0.0125f - mu * mu, 0.f) + 1e-5f);
    }
  }
  __syncthreads();
  stageN<3280>(Wt, w1pp_l + h * 13120, tid);
  __syncthreads();
  {
    float mu = ss[rr * 2], rs = ss[rr * 2 + 1];
    float a2[10] = {};
    for (int k = 0; k < 80; k += 4) {
      float4 av = *(const float4*)&sl[rr * 84 + k];
      #pragma unroll
      for (int m = 0; m < 10; ++m) {
        int c = c16 + 16 * m;
        a2[m] += av.x * Wt[k * 164 + c] + av.y * Wt[(k + 1) * 164 + c]
               + av.z * Wt[(k + 2) * 164 + c] + av.w * Wt[(k + 3) * 164 + c];
      }
    }
    #pragma unroll
    for (int m = 0; m < 10; ++m) {
      int c = h * 160 + c16 + 16 * m;
      float v = rs * a2[m] - mu * rs * uv1[c] + uv1[320 + c];
      v = 0.5f * v * (1.f + erff(v * 0.70710678118f));
      g1[(row0 + rr) * 320 + c] = v;
    }
  }
}

// ---- gfi: ff2 + bias + residual(xin->xout) + in-block LN1 + in_proj-half ----
template<int LAST>
__global__ __launch_bounds__(256, 2) void gfi_k(const float* __restrict__ g1,
    fp w2tp_l, fp fb2, const float* __restrict__ xin, float* __restrict__ xout,
    fp wpnp_l, fp uvn, float* __restrict__ xz) {
  __shared__ float S[17120];
  float* Wt = S;             // [80][164]
  float* As = S + 13120;     // [16][164]
  float* xn = S + 15744;     // [16][84]
  float* ss = S + 17088;     // [32]
  int tid = threadIdx.x, row0 = blockIdx.x * 16, rr = tid >> 4, c16 = tid & 15;
  int h = blockIdx.y;
  float acc2[5] = {};
  for (int kc = 0; kc < 2; ++kc) {
    if (kc) __syncthreads();
    stageN<3280>(Wt, w2tp_l + kc * 13120, tid);
    #pragma unroll
    for (int i = 0; i < 10; ++i) {
      int e = tid + i * 256; int r = e / 160, k = e - r * 160;
      As[r * 164 + k] = g1[(row0 + r) * 320 + kc * 160 + k];
    }
    __syncthreads();
    #pragma unroll 4
    for (int k4 = 0; k4 < 160; k4 += 4) {
      float4 a = *(const float4*)&As[rr * 164 + k4];
      #pragma unroll
      for (int m = 0; m < 5; ++m) {
        float4 w = *(const float4*)&Wt[(c16 + 16 * m) * 164 + k4];
        acc2[m] += a.x * w.x + a.y * w.y + a.z * w.z + a.w * w.w;
      }
    }
  }
  {
    float s = 0.f, q = 0.f;
    #pragma unroll
    for (int m = 0; m < 5; ++m) {
      int c = c16 + 16 * m;
      float v = acc2[m] + fb2[c] + xin[(row0 + rr) * 80 + c];
      xout[(row0 + rr) * 80 + c] = v;   // both y-blocks write identical values
      xn[rr * 84 + c] = v;
      s += v; q += v * v;
    }
    if (!LAST) {
      s += __shfl_xor(s, 1); s += __shfl_xor(s, 2);
      s += __shfl_xor(s, 4); s += __shfl_xor(s, 8);
      q += __shfl_xor(q, 1); q += __shfl_xor(q, 2);
      q += __shfl_xor(q, 4); q += __shfl_xor(q, 8);
      if (c16 == 0) {
        float mu = s * 0.0125f;
        ss[rr * 2] = mu;
        ss[rr * 2 + 1] = rsqrtf(fmaxf(q * 0.0125f - mu * mu, 0.f) + 1e-5f);
      }
    }
  }
  if (!LAST) {
    __syncthreads();
    stageN<3280>(Wt, wpnp_l + h * 13120, tid);
    __syncthreads();
    float mu = ss[rr * 2], rs = ss[rr * 2 + 1];
    float a3[10] = {};
    for (int k = 0; k < 80; k += 4) {
      float4 av = *(const float4*)&xn[rr * 84 + k];
      #pragma unroll
      for (int m = 0; m < 10; ++m) {
        int c = c16 + 16 * m;
        a3[m] += av.x * Wt[k * 164 + c] + av.y * Wt[(k + 1) * 164 + c]
               + av.z * Wt[(k + 2) * 164 + c] + av.w * Wt[(k + 3) * 164 + c];
      }
    }
    #pragma unroll
    for (int m = 0; m < 10; ++m) {
      int c = h * 160 + c16 + 16 * m;
      xz[(row0 + rr) * 320 + c] = rs * a3[m] - mu * rs * uvn[c] + uvn[320 + c];
    }
  }
}

// ---- pooling: per-(b,c) mean/std over T -------------------------------------
__global__ __launch_bounds__(256) void stats_k(const float* __restrict__ x,
                                               float* __restrict__ meanv, float* __restrict__ stdv) {
  int bc = blockIdx.x; int b = bc / C_, c = bc % C_;
  __shared__ float sb[4];
  int tid = threadIdx.x;
  float v[4]; float s = 0.f;
  #pragma unroll
  for (int i = 0; i < 4; ++i) {
    int t = tid + i * 256;
    v[i] = (t < T_) ? x[(b * T_ + t) * C_ + c] : 0.f;
    s += v[i];
  }
  s = blockSum(s, sb);
  float mu = s * (1.f / T_);
  float q = 0.f;
  #pragma unroll
  for (int i = 0; i < 4; ++i) {
    int t = tid + i * 256;
    if (t < T_) { float dd = v[i] - mu; q += dd * dd; }
  }
  q = blockSum(q, sb);
  if (tid == 0) { meanv[bc] = mu; stdv[bc] = sqrtf(fmaxf(q * (1.f / T_), 1e-12f)); }
}

// ---- att1 pack --------------------------------------------------------------
__global__ __launch_bounds__(256) void prep_k(const float* __restrict__ meanv,
    const float* __restrict__ stdv, fp w1, fp ab1, fp g1p, fp b1p, fp m1p, fp v1p,
    float* __restrict__ pack) {
  int idx = blockIdx.x * 256 + threadIdx.x;
  if (idx < 512) {
    int b = idx / 128, dcol = idx % 128;
    float acc = ab1[dcol];
    for (int c = 0; c < C_; ++c) {
      acc += meanv[b * C_ + c] * w1[(C_ + c) * 128 + dcol];
      acc += stdv[b * C_ + c] * w1[(2 * C_ + c) * 128 + dcol];
    }
    pack[idx] = acc;
  } else if (idx < 640) {
    int dcol = idx - 512;
    float kv = g1p[dcol] * rsqrtf(v1p[dcol] + 1e-5f);
    pack[512 + dcol] = kv;
    pack[640 + dcol] = b1p[dcol] - m1p[dcol] * kv;
  }
}

// ---- softmax over T + weighted stats + bn2 ----------------------------------
__global__ __launch_bounds__(256) void pool_k(const float* __restrict__ x,
    const float* __restrict__ scores, fp g2, fp b2, fp m2, fp v2,
    float* __restrict__ pooledn) {
  int bc = blockIdx.x; int b = bc / C_, c = bc % C_;
  __shared__ float sb[4];
  int tid = threadIdx.x;
  float sv[4], xv[4];
  float mx = -1e30f;
  #pragma unroll
  for (int i = 0; i < 4; ++i) {
    int t = tid + i * 256;
    if (t < T_) { sv[i] = scores[(b * T_ + t) * C_ + c]; xv[i] = x[(b * T_ + t) * C_ + c]; }
    else { sv[i] = -1e30f; xv[i] = 0.f; }
    mx = fmaxf(mx, sv[i]);
  }
  mx = blockMax(mx, sb);
  float se = 0.f, sx = 0.f, sxx = 0.f;
  #pragma unroll
  for (int i = 0; i < 4; ++i) {
    float e = expf(sv[i] - mx);
    se += e; sx += e * xv[i]; sxx += e * xv[i] * xv[i];
  }
  se = blockSum(se, sb);
  sx = blockSum(sx, sb);
  sxx = blockSum(sxx, sb);
  if (tid == 0) {
    float mu = sx / se;
    float sg = sqrtf(fmaxf(sxx / se - mu * mu, 1e-12f));
    int j0 = c, j1 = C_ + c;
    pooledn[b * 160 + j0] = (mu - m2[j0]) * rsqrtf(v2[j0] + 1e-5f) * g2[j0] + b2[j0];
    pooledn[b * 160 + j1] = (sg - m2[j1]) * rsqrtf(v2[j1] + 1e-5f) * g2[j1] + b2[j1];
  }
}

// ---- final fc ---------------------------------------------------------------
__global__ __launch_bounds__(256) void fc_k(const float* __restrict__ pooledn, fp fw, fp fb,
                                            float* __restrict__ out) {
  int idx = blockIdx.x * 256 + threadIdx.x;
  if (idx >= 4 * 192) return;
  int b = idx / 192, e = idx % 192;
  float acc = fb[e];
  for (int i = 0; i < 160; ++i) acc += pooledn[b * 160 + i] * fw[i * 192 + e];
  out[idx] = acc;
}

extern "C" void kernel_launch(void* const* d_in, const int* in_sizes, int n_in,
                              void* d_out, int out_size, void* d_ws, size_t ws_size,
                              hipStream_t stream) {
  fp feat   = (fp)d_in[0];
  fp ln1_g  = (fp)d_in[1];  fp ln1_b  = (fp)d_in[2];
  fp in_proj= (fp)d_in[3];
  fp conv_w = (fp)d_in[4];  fp conv_b = (fp)d_in[5];
  fp x_proj = (fp)d_in[6];
  fp dt_w   = (fp)d_in[7];  fp dt_b   = (fp)d_in[8];
  fp A_log  = (fp)d_in[9];  fp Dp     = (fp)d_in[10];
  fp out_proj=(fp)d_in[11];
  fp ln2_g  = (fp)d_in[12]; fp ln2_b  = (fp)d_in[13];
  fp ff_w1  = (fp)d_in[14]; fp ff_b1  = (fp)d_in[15];
  fp ff_w2  = (fp)d_in[16]; fp ff_b2  = (fp)d_in[17];
  fp att_w1 = (fp)d_in[18]; fp att_b1 = (fp)d_in[19];
  fp bn1_g  = (fp)d_in[20]; fp bn1_b  = (fp)d_in[21];
  fp bn1_m  = (fp)d_in[22]; fp bn1_v  = (fp)d_in[23];
  fp att_w2 = (fp)d_in[24]; fp att_b2 = (fp)d_in[25];
  fp bn2_g  = (fp)d_in[26]; fp bn2_b  = (fp)d_in[27];
  fp bn2_m  = (fp)d_in[28]; fp bn2_v  = (fp)d_in[29];
  fp fc_w   = (fp)d_in[30]; fp fc_b   = (fp)d_in[31];

  float* ws   = (float*)d_ws;
  float* x    = ws;               // 256000
  float* xz   = ws + 256000;      // 1024000
  float* xcf  = ws + 1280000;     // 512000
  float* xcb  = ws + 1792000;     // 512000
  float* dbc2 = ws + 2304000;     // 256000 (6400 x 40, padded)
  float* dt2  = ws + 2560000;     // 1024000
  float* hp   = ws + 3584000;     // 655360 (1280 x 256 x 2)
  float* ygcat= ws + 4239360;     // 1024000
  float* meanv= ws + 5263360;     // 320
  float* stdv = ws + 5263680;     // 320
  float* pack = ws + 5264000;     // 768
  float* pooledn = ws + 5264768;  // 640
  float* wp   = ws + 5265408;     // 614400
  float* uvb  = ws + 5879808;     // 15360
  float* mst_x= ws + 5895168;     // 6400
  float* xptp = ws + 5901568;     // 72816
  float* wotp = ws + 5974384;     // 157440
  float* w1pp = ws + 6131824;     // 314880
  float* w2tp = ws + 6446704;     // 314880
  float* wpnp = ws + 6761584;     // 314880
  float* x2   = ws + 7076464;     // 256000  (end 7332464 = 29.3 MiB)
  float* g1   = xz;               // alias: xz free after scanC
  float* a1b  = hp;               // alias: pooling only (409600 < 655360)
  float* sc   = dt2;              // alias: pooling only
  float* xb[2] = { x, x2 };

  prepw_k<<<30, 256, 0, stream>>>(in_proj, ff_w1, ln1_g, ln1_b, ln2_g, ln2_b,
                                  ff_b1, wp, uvb);
  prepg_k<<<4305, 256, 0, stream>>>(out_proj, ff_w2, wp, wotp, w1pp, w2tp, wpnp);
  prepx_k<<<285, 256, 0, stream>>>(x_proj, xptp);
  cmn_k<<<320, 256, 0, stream>>>(feat, x);
  rstat_k<<<200, 256, 0, stream>>>(x, mst_x);
  gw_k<0><<<250, 256, 0, stream>>>(x, wp, uvb, mst_x, nullptr, xz, 320);

  for (int l = 0; l < 12; ++l) {
    cxf_k<<<400, 256, 0, stream>>>(xz, conv_w + l * 640, conv_b + l * 160,
                                   xptp + l * 6068, dt_w + l * 800, dt_b + l * 160,
                                   xcf, xcb, dbc2, dt2);
    scanA_k<<<1280, 256, 0, stream>>>(dt2, xcf, xcb, dbc2, A_log + l * 2560, hp);
    scanC_k<<<1280, 256, 0, stream>>>(dt2, dbc2, xcf, xcb, xz, A_log + l * 2560,
                                      Dp + l * 160, hp, ygcat);
    gof_k<<<dim3(200, 2), 256, 0, stream>>>(ygcat, wotp + l * 13120,
                                            w1pp + l * 26240,
                                            uvb + (2 * l + 1) * 640, g1);
    if (l < 11)
      gfi_k<0><<<dim3(200, 2), 256, 0, stream>>>(g1, w2tp + l * 26240,
                                                 ff_b2 + l * 80, xb[l & 1],
                                                 xb[(l + 1) & 1],
                                                 wpnp + l * 26240,
                                                 uvb + (2 * l + 2) * 640, xz);
    else
      gfi_k<1><<<dim3(200, 2), 256, 0, stream>>>(g1, w2tp + l * 26240,
                                                 ff_b2 + l * 80, xb[l & 1],
                                                 xb[(l + 1) & 1],
                                                 wpnp + l * 26240, uvb, xz);
  }

  stats_k<<<320, 256, 0, stream>>>(x, meanv, stdv);
  prep_k<<<3, 256, 0, stream>>>(meanv, stdv, att_w1, att_b1, bn1_g, bn1_b, bn1_m, bn1_v, pack);
  gw_k<3><<<100, 256, 0, stream>>>(x, att_w1, nullptr, nullptr, pack, a1b, 128);
  gc_k<4, 128, 1><<<200, 256, 0, stream>>>(a1b, att_w2, att_b2, sc, 128);
  pool_k<<<320, 256, 0, stream>>>(x, sc, bn2_g, bn2_b, bn2_m, bn2_v, pooledn);
  fc_k<<<3, 256, 0, stream>>>(pooledn, fc_w, fc_b, (float*)d_out);
}